// Round 1
// 1405.746 us; speedup vs baseline: 1.0425x; 1.0425x over previous
//
#include <hip/hip_runtime.h>
#include <stdint.h>

// ---------------- problem constants ----------------
#define NTOK   16384      // B*S
#define HDIM   1024
#define IDIM   2048
#define NEXP   8
#define NASG   (NTOK*2)   // top-2 assignments

typedef __bf16 bf16x8 __attribute__((ext_vector_type(8)));
typedef float  f32x4  __attribute__((ext_vector_type(4)));

__device__ __forceinline__ unsigned short f2b(float f) {
  unsigned int u = __builtin_bit_cast(unsigned int, f);
  u = (u + 0x7fffu + ((u >> 16) & 1u)) >> 16;   // RNE
  return (unsigned short)u;
}

__device__ __forceinline__ void async16(const void* g, void* l) {
  // global -> LDS DMA, 16B/lane. LDS dest is wave-uniform base + lane*16.
  __builtin_amdgcn_global_load_lds(
      (__attribute__((address_space(1))) void*)(uintptr_t)g,
      (__attribute__((address_space(3))) void*)l,
      16, 0, 0);
}

__device__ __forceinline__ bf16x8 load_frag(const unsigned short* p) {
  uint4 v = *(const uint4*)p;
  return __builtin_bit_cast(bf16x8, v);
}

// ---------------- cast fp32 -> bf16 ----------------
__global__ __launch_bounds__(256) void cast_kernel(const float* __restrict__ in,
                                                   unsigned short* __restrict__ out,
                                                   int n4) {
  int i = blockIdx.x * blockDim.x + threadIdx.x;
  int stride = gridDim.x * blockDim.x;
  for (; i < n4; i += stride) {
    float4 v = ((const float4*)in)[i];
    ushort4 o;
    o.x = f2b(v.x); o.y = f2b(v.y); o.z = f2b(v.z); o.w = f2b(v.w);
    ((ushort4*)out)[i] = o;
  }
}

// ---------------- router: one wave per token ----------------
__global__ __launch_bounds__(256) void router_kernel(const float* __restrict__ x,
                                                     const float* __restrict__ rw,
                                                     int* __restrict__ tok_e,
                                                     float* __restrict__ tok_w,
                                                     int* __restrict__ cnt) {
  int wid = threadIdx.x >> 6, lane = threadIdx.x & 63;
  int t = blockIdx.x * 4 + wid;
  const float* xp = x + (size_t)t * HDIM;
  float xv[16];
#pragma unroll
  for (int j = 0; j < 16; j++) xv[j] = xp[lane + 64 * j];
  float lg[8];
#pragma unroll
  for (int e = 0; e < 8; e++) {
    const float* wp = rw + e * HDIM;
    float s = 0.f;
#pragma unroll
    for (int j = 0; j < 16; j++) s += xv[j] * wp[lane + 64 * j];
#pragma unroll
    for (int off = 32; off > 0; off >>= 1) s += __shfl_xor(s, off, 64);
    lg[e] = s;
  }
  int e0 = 0; float l0 = lg[0];
#pragma unroll
  for (int e = 1; e < 8; e++) if (lg[e] > l0) { l0 = lg[e]; e0 = e; }
  int e1 = -1; float l1 = -3.0e38f;
#pragma unroll
  for (int e = 0; e < 8; e++) if (e != e0 && lg[e] > l1) { l1 = lg[e]; e1 = e; }
  float w0 = 1.f / (1.f + __expf(l1 - l0));   // == renormalized top-2 softmax
  if (lane == 0) {
    tok_e[t * 2 + 0] = e0; tok_e[t * 2 + 1] = e1;
    tok_w[t * 2 + 0] = w0; tok_w[t * 2 + 1] = 1.f - w0;
    atomicAdd(&cnt[e0], 1);
    atomicAdd(&cnt[e1], 1);
  }
}

// ---------------- scan (8 experts) ----------------
__global__ void scan_kernel(const int* __restrict__ cnt, int* __restrict__ offs) {
  if (threadIdx.x == 0) {
    int s = 0;
    for (int e = 0; e < NEXP; e++) { offs[e] = s; s += cnt[e]; }
    offs[NEXP] = s;
  }
}

// ---------------- scatter tokens into expert lists ----------------
__global__ __launch_bounds__(256) void scatter_kernel(const int* __restrict__ tok_e,
                                                      const float* __restrict__ tok_w,
                                                      const int* __restrict__ offs,
                                                      int* __restrict__ cursor,
                                                      int* __restrict__ asg_tok,
                                                      float* __restrict__ asg_w) {
  int t = blockIdx.x * blockDim.x + threadIdx.x;
  if (t < NTOK) {
#pragma unroll
    for (int s = 0; s < 2; s++) {
      int e = tok_e[t * 2 + s];
      int p = atomicAdd(&cursor[e], 1);
      asg_tok[offs[e] + p] = t;
      asg_w[offs[e] + p] = tok_w[t * 2 + s];
    }
  }
}

// ---------------- GEMM1: hact = silu(X*Wg^T) * (X*Wu^T), grouped, dual-B fused ----------------
// grid = (ichunk/128, 128, NEXP); tile 128x128, BK=64, K=HDIM
// LDS tiles XOR-swizzled (T2, rule #21): linear global_load_lds dest,
// pre-swizzled GLOBAL source column (g8 ^ row8&7), swizzled ds_read column.
// Unswizzled, row stride = 128B = 32 banks -> 16-lane same-bank group = 2x read time.
__global__ __launch_bounds__(256, 2) void gemm1_kernel(
    const unsigned short* __restrict__ xb,
    const unsigned short* __restrict__ wg,
    const unsigned short* __restrict__ wu,
    const int* __restrict__ asg_tok,
    const int* __restrict__ offs,
    unsigned short* __restrict__ hact,
    int i0, int ichunk) {
  int nt = blockIdx.x;
  int mt = blockIdx.y;
  int e  = blockIdx.z;
  int base = offs[e];
  int rows = offs[e + 1] - base;
  if (mt * 128 >= rows) return;

  __shared__ __align__(16) unsigned short lA [128 * 64];
  __shared__ __align__(16) unsigned short lBg[128 * 64];
  __shared__ __align__(16) unsigned short lBu[128 * 64];

  int t = threadIdx.x;
  int lane = t & 63, wid = t >> 6;
  int wm = wid & 1, wn = wid >> 1;
  int mrow = lane & 15, quad = lane >> 4;
  int row8 = t >> 3, g8 = t & 7;
  int g8s = g8 ^ (row8 & 7);      // swizzled source column group
  int sw  = mrow & 7;             // read-side swizzle key (LDS row & 7)

  const unsigned short* aptr[4];
  const unsigned short* bgptr[4];
  const unsigned short* buptr[4];
#pragma unroll
  for (int r = 0; r < 4; r++) {
    int arow = mt * 128 + r * 32 + row8;
    if (arow >= rows) arow = rows - 1;
    int tok = asg_tok[base + arow];
    aptr[r] = xb + (size_t)tok * HDIM + g8s * 8;
    int brow = i0 + nt * 128 + r * 32 + row8;
    bgptr[r] = wg + ((size_t)e * IDIM + brow) * HDIM + g8s * 8;
    buptr[r] = wu + ((size_t)e * IDIM + brow) * HDIM + g8s * 8;
  }

  f32x4 accg[4][4], accu[4][4];
#pragma unroll
  for (int i = 0; i < 4; i++)
#pragma unroll
    for (int j = 0; j < 4; j++) { accg[i][j] = (f32x4)(0.f); accu[i][j] = (f32x4)(0.f); }

  for (int k0 = 0; k0 < HDIM; k0 += 64) {
#pragma unroll
    for (int r = 0; r < 4; r++) {
      async16(aptr[r]  + k0, &lA [r * 2048 + t * 8]);
      async16(bgptr[r] + k0, &lBg[r * 2048 + t * 8]);
      async16(buptr[r] + k0, &lBu[r * 2048 + t * 8]);
    }
    __syncthreads();
#pragma unroll
    for (int kh = 0; kh < 2; kh++) {
      int ko = ((((kh << 2) | quad) ^ sw) << 3);   // swizzled column (shorts)
      bf16x8 af[4], bgf[4], buf2[4];
#pragma unroll
      for (int i = 0; i < 4; i++) {
        af[i]   = load_frag(&lA [(wm * 64 + i * 16 + mrow) * 64 + ko]);
        bgf[i]  = load_frag(&lBg[(wn * 64 + i * 16 + mrow) * 64 + ko]);
        buf2[i] = load_frag(&lBu[(wn * 64 + i * 16 + mrow) * 64 + ko]);
      }
#pragma unroll
      for (int mi = 0; mi < 4; mi++)
#pragma unroll
        for (int ni = 0; ni < 4; ni++) {
          accg[mi][ni] = __builtin_amdgcn_mfma_f32_16x16x32_bf16(af[mi], bgf[ni],  accg[mi][ni], 0, 0, 0);
          accu[mi][ni] = __builtin_amdgcn_mfma_f32_16x16x32_bf16(af[mi], buf2[ni], accu[mi][ni], 0, 0, 0);
        }
    }
    __syncthreads();
  }

  // epilogue: silu(g)*u -> bf16 (hact is [NASG][ichunk], chunk-local cols)
#pragma unroll
  for (int mi = 0; mi < 4; mi++) {
#pragma unroll
    for (int r = 0; r < 4; r++) {
      int row = mt * 128 + wm * 64 + mi * 16 + quad * 4 + r;
      if (row < rows) {
        size_t rb = (size_t)(base + row) * ichunk + nt * 128 + wn * 64;
#pragma unroll
        for (int ni = 0; ni < 4; ni++) {
          float g = accg[mi][ni][r];
          float u = accu[mi][ni][r];
          float h = g / (1.f + __expf(-g)) * u;
          hact[rb + ni * 16 + mrow] = f2b(h);
        }
      }
    }
  }
}

// ---------------- GEMM2: out += w * (hact * Wd^T), grouped ----------------
// grid = (HDIM/256, 128, NEXP); tile 128x256, BK=64, K=ichunk
// Widened N-tile: 43.7 FLOP per LDS byte (was 32.8) so the LDS-read pipe
// (85 B/cyc/CU achievable) no longer outruns the MFMA pipe; same XOR swizzle.
__global__ __launch_bounds__(256, 2) void gemm2_kernel(
    const unsigned short* __restrict__ hact,
    const unsigned short* __restrict__ wd,
    const int* __restrict__ asg_tok,
    const float* __restrict__ asg_w,
    const int* __restrict__ offs,
    float* __restrict__ out,
    int i0, int ichunk) {
  int nt = blockIdx.x;
  int mt = blockIdx.y;
  int e  = blockIdx.z;
  int base = offs[e];
  int rows = offs[e + 1] - base;
  if (mt * 128 >= rows) return;

  __shared__ __align__(16) unsigned short lA[128 * 64];   // 16 KB
  __shared__ __align__(16) unsigned short lB[256 * 64];   // 32 KB

  int t = threadIdx.x;
  int lane = t & 63, wid = t >> 6;
  int wm = wid & 1, wn = wid >> 1;          // 2x2 waves; each wave: 64 rows x 128 cols
  int mrow = lane & 15, quad = lane >> 4;
  int row8 = t >> 3, g8 = t & 7;
  int g8s = g8 ^ (row8 & 7);
  int sw  = mrow & 7;

  const unsigned short* aptr[4];
  const unsigned short* bptr[8];
#pragma unroll
  for (int r = 0; r < 4; r++) {
    int arow = mt * 128 + r * 32 + row8;
    if (arow >= rows) arow = rows - 1;
    aptr[r] = hact + (size_t)(base + arow) * ichunk + g8s * 8;
  }
#pragma unroll
  for (int r = 0; r < 8; r++) {
    int brow = nt * 256 + r * 32 + row8;
    bptr[r] = wd + ((size_t)e * HDIM + brow) * IDIM + i0 + g8s * 8;
  }

  f32x4 acc[4][8];
#pragma unroll
  for (int i = 0; i < 4; i++)
#pragma unroll
    for (int j = 0; j < 8; j++) acc[i][j] = (f32x4)(0.f);

  for (int k0 = 0; k0 < ichunk; k0 += 64) {
#pragma unroll
    for (int r = 0; r < 4; r++) async16(aptr[r] + k0, &lA[r * 2048 + t * 8]);
#pragma unroll
    for (int r = 0; r < 8; r++) async16(bptr[r] + k0, &lB[r * 2048 + t * 8]);
    __syncthreads();
#pragma unroll
    for (int kh = 0; kh < 2; kh++) {
      int ko = ((((kh << 2) | quad) ^ sw) << 3);
      bf16x8 af[4], bf[8];
#pragma unroll
      for (int i = 0; i < 4; i++)
        af[i] = load_frag(&lA[(wm * 64 + i * 16 + mrow) * 64 + ko]);
#pragma unroll
      for (int i = 0; i < 8; i++)
        bf[i] = load_frag(&lB[(wn * 128 + i * 16 + mrow) * 64 + ko]);
#pragma unroll
      for (int mi = 0; mi < 4; mi++)
#pragma unroll
        for (int ni = 0; ni < 8; ni++)
          acc[mi][ni] = __builtin_amdgcn_mfma_f32_16x16x32_bf16(af[mi], bf[ni], acc[mi][ni], 0, 0, 0);
    }
    __syncthreads();
  }

  // epilogue: scale by routing weight, atomic-accumulate into out
#pragma unroll
  for (int mi = 0; mi < 4; mi++) {
#pragma unroll
    for (int r = 0; r < 4; r++) {
      int row = mt * 128 + wm * 64 + mi * 16 + quad * 4 + r;
      if (row < rows) {
        int ar = base + row;
        int tok = asg_tok[ar];
        float w = asg_w[ar];
        float* op = out + (size_t)tok * HDIM + nt * 256 + wn * 128;
#pragma unroll
        for (int ni = 0; ni < 8; ni++)
          atomicAdd(&op[ni * 16 + mrow], w * acc[mi][ni][r]);
      }
    }
  }
}

// ---------------- launch ----------------
extern "C" void kernel_launch(void* const* d_in, const int* in_sizes, int n_in,
                              void* d_out, int out_size, void* d_ws, size_t ws_size,
                              hipStream_t stream) {
  const float* x  = (const float*)d_in[0];
  const float* rw = (const float*)d_in[1];
  const float* gw = (const float*)d_in[2];
  const float* uw = (const float*)d_in[3];
  const float* dw = (const float*)d_in[4];
  float* out = (float*)d_out;
  char* ws = (char*)d_ws;

  // ---- workspace layout (kept well under ws_size) ----
  // weights bf16: 3 * 8*2048*1024*2 = 100,663,296 B
  unsigned short* wg = (unsigned short*)ws;
  unsigned short* wu = wg + (size_t)NEXP * IDIM * HDIM;
  unsigned short* wd = wu + (size_t)NEXP * IDIM * HDIM;
  char* p = ws + 3ull * NEXP * IDIM * HDIM * 2;
  int*   asg_tok = (int*)p;            p += (size_t)NASG * 4;
  float* asg_w   = (float*)p;          p += (size_t)NASG * 4;
  int*   tok_e   = (int*)p;            p += (size_t)NASG * 4;
  float* tok_w   = (float*)p;          p += (size_t)NASG * 4;
  int*   meta    = (int*)p;            p += 128;
  int* cnt    = meta;          // 8
  int* cursor = meta + 8;      // 8
  int* offs   = meta + 16;     // 9

  // Pick I-chunking so hact fits. Primary path: ichunk=2048, xb borrowed
  // from d_out (dead until gemm2), hact in ws -> total ws use 235.4 MB.
  int ichunk; bool xb_in_out;
  if      (ws_size >= 235405440ull) { ichunk = 2048; xb_in_out = true;  }
  else if (ws_size >= 201851008ull) { ichunk = 1024; xb_in_out = false; }
  else if (ws_size >= 168296576ull) { ichunk = 512;  xb_in_out = false; }
  else                              { ichunk = 256;  xb_in_out = false; }

  unsigned short* xb;
  unsigned short* hact;
  if (xb_in_out) {
    xb   = (unsigned short*)d_out;       // first 33.5 MB of the 67 MB output
    hact = (unsigned short*)p;           // 134.2 MB
  } else {
    xb   = (unsigned short*)p;
    hact = (unsigned short*)(p + (size_t)NTOK * HDIM * 2);
  }

  hipMemsetAsync(meta, 0, 64, stream);   // cnt + cursor

  // fp32 -> bf16 casts
  cast_kernel<<<4096, 256, 0, stream>>>(gw, wg, (NEXP * IDIM * HDIM) / 4);
  cast_kernel<<<4096, 256, 0, stream>>>(uw, wu, (NEXP * IDIM * HDIM) / 4);
  cast_kernel<<<4096, 256, 0, stream>>>(dw, wd, (NEXP * HDIM * IDIM) / 4);
  cast_kernel<<<4096, 256, 0, stream>>>(x,  xb, (NTOK * HDIM) / 4);

  router_kernel<<<NTOK / 4, 256, 0, stream>>>(x, rw, tok_e, tok_w, cnt);
  scan_kernel<<<1, 64, 0, stream>>>(cnt, offs);
  scatter_kernel<<<NTOK / 256, 256, 0, stream>>>(tok_e, tok_w, offs, cursor, asg_tok, asg_w);

  if (xb_in_out) {
    gemm1_kernel<<<dim3(16, 128, NEXP), 256, 0, stream>>>(xb, wg, wu, asg_tok, offs, hact, 0, 2048);
    // xb (in d_out) is dead now; zero d_out for atomic accumulation
    hipMemsetAsync(d_out, 0, (size_t)out_size * sizeof(float), stream);
    gemm2_kernel<<<dim3(HDIM / 256, 128, NEXP), 256, 0, stream>>>(hact, wd, asg_tok, asg_w, offs, out, 0, 2048);
  } else {
    hipMemsetAsync(d_out, 0, (size_t)out_size * sizeof(float), stream);
    for (int i0 = 0; i0 < IDIM; i0 += ichunk) {
      gemm1_kernel<<<dim3(ichunk / 128, 128, NEXP), 256, 0, stream>>>(xb, wg, wu, asg_tok, offs, hact, i0, ichunk);
      gemm2_kernel<<<dim3(HDIM / 256, 128, NEXP), 256, 0, stream>>>(hact, wd, asg_tok, asg_w, offs, out, i0, ichunk);
    }
  }
}

// Round 2
// 853.240 us; speedup vs baseline: 1.7176x; 1.6475x over previous
//
#include <hip/hip_runtime.h>
#include <stdint.h>

// ---------------- problem constants ----------------
#define NTOK   16384      // B*S
#define HDIM   1024
#define IDIM   2048
#define NEXP   8
#define NASG   (NTOK*2)   // top-2 assignments
#define RBLK   512        // router grid blocks (2 per CU)

typedef __bf16 bf16x8 __attribute__((ext_vector_type(8)));
typedef float  f32x4  __attribute__((ext_vector_type(4)));

__device__ __forceinline__ unsigned short f2b(float f) {
  unsigned int u = __builtin_bit_cast(unsigned int, f);
  u = (u + 0x7fffu + ((u >> 16) & 1u)) >> 16;   // RNE
  return (unsigned short)u;
}

__device__ __forceinline__ void async16(const void* g, void* l) {
  // global -> LDS DMA, 16B/lane. LDS dest is wave-uniform base + lane*16.
  __builtin_amdgcn_global_load_lds(
      (__attribute__((address_space(1))) void*)(uintptr_t)g,
      (__attribute__((address_space(3))) void*)l,
      16, 0, 0);
}

__device__ __forceinline__ bf16x8 load_frag(const unsigned short* p) {
  uint4 v = *(const uint4*)p;
  return __builtin_bit_cast(bf16x8, v);
}

// ---------------- cast fp32 -> bf16 ----------------
__global__ __launch_bounds__(256) void cast_kernel(const float* __restrict__ in,
                                                   unsigned short* __restrict__ out,
                                                   int n4) {
  int i = blockIdx.x * blockDim.x + threadIdx.x;
  int stride = gridDim.x * blockDim.x;
  for (; i < n4; i += stride) {
    float4 v = ((const float4*)in)[i];
    ushort4 o;
    o.x = f2b(v.x); o.y = f2b(v.y); o.z = f2b(v.z); o.w = f2b(v.w);
    ((ushort4*)out)[i] = o;
  }
}

// ---------------- router: grid-stride waves, LDS histogram, NO global atomics ----
// Old version: 32768 atomicAdds onto one 64B line (cnt[8]) = 387us of same-line
// L2 RMW serialization (11.8ns each, VALUBusy 2%). Now each block stores its
// 8-bin LDS histogram to hist[block][8] (plain stores); scan sums them.
// Also fuses the x fp32->bf16 cast (lanes already hold the row).
__global__ __launch_bounds__(256) void router_kernel(const float* __restrict__ x,
                                                     const float* __restrict__ rw,
                                                     unsigned short* __restrict__ xb,
                                                     int* __restrict__ tok_e,
                                                     float* __restrict__ tok_w,
                                                     int* __restrict__ hist) {
  __shared__ float srw[NEXP * HDIM];   // 32 KB: router weights, read 8x per token
  __shared__ int hcnt[NEXP];
  int tid = threadIdx.x;
  for (int i = tid; i < (NEXP * HDIM) / 4; i += 256)
    ((float4*)srw)[i] = ((const float4*)rw)[i];
  if (tid < NEXP) hcnt[tid] = 0;
  __syncthreads();

  int wid = tid >> 6, lane = tid & 63;
  int gwave = blockIdx.x * 4 + wid;
  int nw = RBLK * 4;
  for (int t = gwave; t < NTOK; t += nw) {
    const float* xp = x + (size_t)t * HDIM;
    float xv[16];
#pragma unroll
    for (int j = 0; j < 16; j++) xv[j] = xp[lane + 64 * j];
    // fused cast: write bf16 row while it's in registers
    unsigned short* xbp = xb + (size_t)t * HDIM;
#pragma unroll
    for (int j = 0; j < 16; j++) xbp[lane + 64 * j] = f2b(xv[j]);
    float lg[8];
#pragma unroll
    for (int e = 0; e < 8; e++) {
      const float* wp = srw + e * HDIM;
      float s = 0.f;
#pragma unroll
      for (int j = 0; j < 16; j++) s += xv[j] * wp[lane + 64 * j];
#pragma unroll
      for (int off = 32; off > 0; off >>= 1) s += __shfl_xor(s, off, 64);
      lg[e] = s;
    }
    int e0 = 0; float l0 = lg[0];
#pragma unroll
    for (int e = 1; e < 8; e++) if (lg[e] > l0) { l0 = lg[e]; e0 = e; }
    int e1 = -1; float l1 = -3.0e38f;
#pragma unroll
    for (int e = 0; e < 8; e++) if (e != e0 && lg[e] > l1) { l1 = lg[e]; e1 = e; }
    float w0 = 1.f / (1.f + __expf(l1 - l0));   // == renormalized top-2 softmax
    if (lane == 0) {
      tok_e[t * 2 + 0] = e0; tok_e[t * 2 + 1] = e1;
      tok_w[t * 2 + 0] = w0; tok_w[t * 2 + 1] = 1.f - w0;
      atomicAdd(&hcnt[e0], 1);   // LDS atomic: cheap
      atomicAdd(&hcnt[e1], 1);
    }
  }
  __syncthreads();
  if (tid < NEXP) hist[blockIdx.x * NEXP + tid] = hcnt[tid];  // plain store
}

// ---------------- scan: one wave sums hist[RBLK][8] -> offs ----------------
__global__ void scan_kernel(const int* __restrict__ hist, int* __restrict__ offs) {
  int lane = threadIdx.x & 63;
  int tot[NEXP];
#pragma unroll
  for (int e = 0; e < NEXP; e++) {
    int s = 0;
    for (int b = lane; b < RBLK; b += 64) s += hist[b * NEXP + e];
#pragma unroll
    for (int off = 32; off > 0; off >>= 1) s += __shfl_xor(s, off, 64);
    tot[e] = s;
  }
  if (lane == 0) {
    int s = 0;
#pragma unroll
    for (int e = 0; e < NEXP; e++) { offs[e] = s; s += tot[e]; }
    offs[NEXP] = s;
  }
}

// ---------------- scatter: block-level range reservation ----------------
// 64 blocks x 256 tokens. LDS histogram -> 8 global atomics per block
// (512 total vs 32768) -> LDS-prefix placement.
__global__ __launch_bounds__(256) void scatter_kernel(const int* __restrict__ tok_e,
                                                      const float* __restrict__ tok_w,
                                                      const int* __restrict__ offs,
                                                      int* __restrict__ cursor,
                                                      int* __restrict__ asg_tok,
                                                      float* __restrict__ asg_w) {
  __shared__ int lcnt[NEXP], lbase[NEXP], lpos[NEXP];
  int tid = threadIdx.x;
  if (tid < NEXP) { lcnt[tid] = 0; lpos[tid] = 0; }
  __syncthreads();
  int t = blockIdx.x * 256 + tid;
  int e0 = tok_e[t * 2 + 0], e1 = tok_e[t * 2 + 1];
  float w0 = tok_w[t * 2 + 0], w1 = tok_w[t * 2 + 1];
  atomicAdd(&lcnt[e0], 1);
  atomicAdd(&lcnt[e1], 1);
  __syncthreads();
  if (tid < NEXP) {
    int c = lcnt[tid];
    lbase[tid] = c ? atomicAdd(&cursor[tid], c) : 0;
  }
  __syncthreads();
  int p0 = atomicAdd(&lpos[e0], 1);
  int q0 = offs[e0] + lbase[e0] + p0;
  asg_tok[q0] = t; asg_w[q0] = w0;
  int p1 = atomicAdd(&lpos[e1], 1);
  int q1 = offs[e1] + lbase[e1] + p1;
  asg_tok[q1] = t; asg_w[q1] = w1;
}

// ---------------- GEMM1: hact = silu(X*Wg^T) * (X*Wu^T), grouped, dual-B fused ----------------
// grid = (ichunk/128, 128, NEXP); tile 128x128, BK=64, K=HDIM
// LDS tiles XOR-swizzled (T2, rule #21): linear global_load_lds dest,
// pre-swizzled GLOBAL source column (g8 ^ row8&7), swizzled ds_read column.
__global__ __launch_bounds__(256, 2) void gemm1_kernel(
    const unsigned short* __restrict__ xb,
    const unsigned short* __restrict__ wg,
    const unsigned short* __restrict__ wu,
    const int* __restrict__ asg_tok,
    const int* __restrict__ offs,
    unsigned short* __restrict__ hact,
    int i0, int ichunk) {
  int nt = blockIdx.x;
  int mt = blockIdx.y;
  int e  = blockIdx.z;
  int base = offs[e];
  int rows = offs[e + 1] - base;
  if (mt * 128 >= rows) return;

  __shared__ __align__(16) unsigned short lA [128 * 64];
  __shared__ __align__(16) unsigned short lBg[128 * 64];
  __shared__ __align__(16) unsigned short lBu[128 * 64];

  int t = threadIdx.x;
  int lane = t & 63, wid = t >> 6;
  int wm = wid & 1, wn = wid >> 1;
  int mrow = lane & 15, quad = lane >> 4;
  int row8 = t >> 3, g8 = t & 7;
  int g8s = g8 ^ (row8 & 7);      // swizzled source column group
  int sw  = mrow & 7;             // read-side swizzle key (LDS row & 7)

  const unsigned short* aptr[4];
  const unsigned short* bgptr[4];
  const unsigned short* buptr[4];
#pragma unroll
  for (int r = 0; r < 4; r++) {
    int arow = mt * 128 + r * 32 + row8;
    if (arow >= rows) arow = rows - 1;
    int tok = asg_tok[base + arow];
    aptr[r] = xb + (size_t)tok * HDIM + g8s * 8;
    int brow = i0 + nt * 128 + r * 32 + row8;
    bgptr[r] = wg + ((size_t)e * IDIM + brow) * HDIM + g8s * 8;
    buptr[r] = wu + ((size_t)e * IDIM + brow) * HDIM + g8s * 8;
  }

  f32x4 accg[4][4], accu[4][4];
#pragma unroll
  for (int i = 0; i < 4; i++)
#pragma unroll
    for (int j = 0; j < 4; j++) { accg[i][j] = (f32x4)(0.f); accu[i][j] = (f32x4)(0.f); }

  for (int k0 = 0; k0 < HDIM; k0 += 64) {
#pragma unroll
    for (int r = 0; r < 4; r++) {
      async16(aptr[r]  + k0, &lA [r * 2048 + t * 8]);
      async16(bgptr[r] + k0, &lBg[r * 2048 + t * 8]);
      async16(buptr[r] + k0, &lBu[r * 2048 + t * 8]);
    }
    __syncthreads();
#pragma unroll
    for (int kh = 0; kh < 2; kh++) {
      int ko = ((((kh << 2) | quad) ^ sw) << 3);   // swizzled column (shorts)
      bf16x8 af[4], bgf[4], buf2[4];
#pragma unroll
      for (int i = 0; i < 4; i++) {
        af[i]   = load_frag(&lA [(wm * 64 + i * 16 + mrow) * 64 + ko]);
        bgf[i]  = load_frag(&lBg[(wn * 64 + i * 16 + mrow) * 64 + ko]);
        buf2[i] = load_frag(&lBu[(wn * 64 + i * 16 + mrow) * 64 + ko]);
      }
#pragma unroll
      for (int mi = 0; mi < 4; mi++)
#pragma unroll
        for (int ni = 0; ni < 4; ni++) {
          accg[mi][ni] = __builtin_amdgcn_mfma_f32_16x16x32_bf16(af[mi], bgf[ni],  accg[mi][ni], 0, 0, 0);
          accu[mi][ni] = __builtin_amdgcn_mfma_f32_16x16x32_bf16(af[mi], buf2[ni], accu[mi][ni], 0, 0, 0);
        }
    }
    __syncthreads();
  }

  // epilogue: silu(g)*u -> bf16 (hact is [NASG][ichunk], chunk-local cols)
#pragma unroll
  for (int mi = 0; mi < 4; mi++) {
#pragma unroll
    for (int r = 0; r < 4; r++) {
      int row = mt * 128 + wm * 64 + mi * 16 + quad * 4 + r;
      if (row < rows) {
        size_t rb = (size_t)(base + row) * ichunk + nt * 128 + wn * 64;
#pragma unroll
        for (int ni = 0; ni < 4; ni++) {
          float g = accg[mi][ni][r];
          float u = accu[mi][ni][r];
          float h = g / (1.f + __expf(-g)) * u;
          hact[rb + ni * 16 + mrow] = f2b(h);
        }
      }
    }
  }
}

// ---------------- GEMM2: out += w * (hact * Wd^T), grouped ----------------
// grid = (HDIM/256, 128, NEXP); tile 128x256, BK=64, K=ichunk
__global__ __launch_bounds__(256, 2) void gemm2_kernel(
    const unsigned short* __restrict__ hact,
    const unsigned short* __restrict__ wd,
    const int* __restrict__ asg_tok,
    const float* __restrict__ asg_w,
    const int* __restrict__ offs,
    float* __restrict__ out,
    int i0, int ichunk) {
  int nt = blockIdx.x;
  int mt = blockIdx.y;
  int e  = blockIdx.z;
  int base = offs[e];
  int rows = offs[e + 1] - base;
  if (mt * 128 >= rows) return;

  __shared__ __align__(16) unsigned short lA[128 * 64];   // 16 KB
  __shared__ __align__(16) unsigned short lB[256 * 64];   // 32 KB

  int t = threadIdx.x;
  int lane = t & 63, wid = t >> 6;
  int wm = wid & 1, wn = wid >> 1;          // 2x2 waves; each wave: 64 rows x 128 cols
  int mrow = lane & 15, quad = lane >> 4;
  int row8 = t >> 3, g8 = t & 7;
  int g8s = g8 ^ (row8 & 7);
  int sw  = mrow & 7;

  const unsigned short* aptr[4];
  const unsigned short* bptr[8];
#pragma unroll
  for (int r = 0; r < 4; r++) {
    int arow = mt * 128 + r * 32 + row8;
    if (arow >= rows) arow = rows - 1;
    aptr[r] = hact + (size_t)(base + arow) * ichunk + g8s * 8;
  }
#pragma unroll
  for (int r = 0; r < 8; r++) {
    int brow = nt * 256 + r * 32 + row8;
    bptr[r] = wd + ((size_t)e * HDIM + brow) * IDIM + i0 + g8s * 8;
  }

  f32x4 acc[4][8];
#pragma unroll
  for (int i = 0; i < 4; i++)
#pragma unroll
    for (int j = 0; j < 8; j++) acc[i][j] = (f32x4)(0.f);

  for (int k0 = 0; k0 < ichunk; k0 += 64) {
#pragma unroll
    for (int r = 0; r < 4; r++) async16(aptr[r] + k0, &lA[r * 2048 + t * 8]);
#pragma unroll
    for (int r = 0; r < 8; r++) async16(bptr[r] + k0, &lB[r * 2048 + t * 8]);
    __syncthreads();
#pragma unroll
    for (int kh = 0; kh < 2; kh++) {
      int ko = ((((kh << 2) | quad) ^ sw) << 3);
      bf16x8 af[4], bf[8];
#pragma unroll
      for (int i = 0; i < 4; i++)
        af[i] = load_frag(&lA[(wm * 64 + i * 16 + mrow) * 64 + ko]);
#pragma unroll
      for (int i = 0; i < 8; i++)
        bf[i] = load_frag(&lB[(wn * 128 + i * 16 + mrow) * 64 + ko]);
#pragma unroll
      for (int mi = 0; mi < 4; mi++)
#pragma unroll
        for (int ni = 0; ni < 8; ni++)
          acc[mi][ni] = __builtin_amdgcn_mfma_f32_16x16x32_bf16(af[mi], bf[ni], acc[mi][ni], 0, 0, 0);
    }
    __syncthreads();
  }

  // epilogue: scale by routing weight, atomic-accumulate into out
#pragma unroll
  for (int mi = 0; mi < 4; mi++) {
#pragma unroll
    for (int r = 0; r < 4; r++) {
      int row = mt * 128 + wm * 64 + mi * 16 + quad * 4 + r;
      if (row < rows) {
        int ar = base + row;
        int tok = asg_tok[ar];
        float w = asg_w[ar];
        float* op = out + (size_t)tok * HDIM + nt * 256 + wn * 128;
#pragma unroll
        for (int ni = 0; ni < 8; ni++)
          atomicAdd(&op[ni * 16 + mrow], w * acc[mi][ni][r]);
      }
    }
  }
}

// ---------------- launch ----------------
extern "C" void kernel_launch(void* const* d_in, const int* in_sizes, int n_in,
                              void* d_out, int out_size, void* d_ws, size_t ws_size,
                              hipStream_t stream) {
  const float* x  = (const float*)d_in[0];
  const float* rw = (const float*)d_in[1];
  const float* gw = (const float*)d_in[2];
  const float* uw = (const float*)d_in[3];
  const float* dw = (const float*)d_in[4];
  float* out = (float*)d_out;
  char* ws = (char*)d_ws;

  // ---- workspace layout (unchanged footprint: 235,405,440 B on primary path) ----
  unsigned short* wg = (unsigned short*)ws;
  unsigned short* wu = wg + (size_t)NEXP * IDIM * HDIM;
  unsigned short* wd = wu + (size_t)NEXP * IDIM * HDIM;
  char* p = ws + 3ull * NEXP * IDIM * HDIM * 2;
  int*   asg_tok = (int*)p;            p += (size_t)NASG * 4;
  float* asg_w   = (float*)p;          p += (size_t)NASG * 4;
  int*   tok_e   = (int*)p;            p += (size_t)NASG * 4;
  float* tok_w   = (float*)p;          p += (size_t)NASG * 4;
  int*   meta    = (int*)p;            p += 128;
  int* cursor = meta;          // 8
  int* offs   = meta + 8;      // 9

  // hist[RBLK][8] lives in the upper half of d_out (dead until the pre-gemm2
  // memset; scan consumes it long before that).
  int* hist = (int*)((char*)d_out + (40ull << 20));

  int ichunk; bool xb_in_out;
  if      (ws_size >= 235405440ull) { ichunk = 2048; xb_in_out = true;  }
  else if (ws_size >= 201851008ull) { ichunk = 1024; xb_in_out = false; }
  else if (ws_size >= 168296576ull) { ichunk = 512;  xb_in_out = false; }
  else                              { ichunk = 256;  xb_in_out = false; }

  unsigned short* xb;
  unsigned short* hact;
  if (xb_in_out) {
    xb   = (unsigned short*)d_out;       // first 33.5 MB of the 67 MB output
    hact = (unsigned short*)p;           // 134.2 MB
  } else {
    xb   = (unsigned short*)p;
    hact = (unsigned short*)(p + (size_t)NTOK * HDIM * 2);
  }

  hipMemsetAsync(meta, 0, 64, stream);   // cursor

  // fp32 -> bf16 weight casts (x cast fused into router)
  cast_kernel<<<4096, 256, 0, stream>>>(gw, wg, (NEXP * IDIM * HDIM) / 4);
  cast_kernel<<<4096, 256, 0, stream>>>(uw, wu, (NEXP * IDIM * HDIM) / 4);
  cast_kernel<<<4096, 256, 0, stream>>>(dw, wd, (NEXP * HDIM * IDIM) / 4);

  router_kernel<<<RBLK, 256, 0, stream>>>(x, rw, xb, tok_e, tok_w, hist);
  scan_kernel<<<1, 64, 0, stream>>>(hist, offs);
  scatter_kernel<<<NTOK / 256, 256, 0, stream>>>(tok_e, tok_w, offs, cursor, asg_tok, asg_w);

  if (xb_in_out) {
    gemm1_kernel<<<dim3(16, 128, NEXP), 256, 0, stream>>>(xb, wg, wu, asg_tok, offs, hact, 0, 2048);
    // xb (in d_out) is dead now; zero d_out for atomic accumulation
    hipMemsetAsync(d_out, 0, (size_t)out_size * sizeof(float), stream);
    gemm2_kernel<<<dim3(HDIM / 256, 128, NEXP), 256, 0, stream>>>(hact, wd, asg_tok, asg_w, offs, out, 0, 2048);
  } else {
    hipMemsetAsync(d_out, 0, (size_t)out_size * sizeof(float), stream);
    for (int i0 = 0; i0 < IDIM; i0 += ichunk) {
      gemm1_kernel<<<dim3(ichunk / 128, 128, NEXP), 256, 0, stream>>>(xb, wg, wu, asg_tok, offs, hact, i0, ichunk);
      gemm2_kernel<<<dim3(HDIM / 256, 128, NEXP), 256, 0, stream>>>(hact, wd, asg_tok, asg_w, offs, out, i0, ichunk);
    }
  }
}